// Round 2
// baseline (25.276 us; speedup 1.0000x reference)
//
#include <hip/hip_runtime.h>

// Sigma = R * diag(exp(ls))^2 * R^T per gaussian.
// Memory-bound: 28 B in + 36 B out per element, 128 MB total -> ~20 us floor.

constexpr int BLK = 256;

using f32x4 = __attribute__((ext_vector_type(4))) float;

__global__ __launch_bounds__(BLK) void gauss_covar_kernel(
    const f32x4* __restrict__ quats,       // [N] (w,x,y,z)
    const f32x4* __restrict__ ls4,         // log_scales as float4, N*3/4 elems
    f32x4*       __restrict__ out4,        // out as float4, N*9/4 elems
    int n, int n_ls4, int n_out4)
{
    __shared__ float s_scale[BLK * 3];   // 3 KB
    __shared__ float s_out[BLK * 9];     // 9 KB

    const int tid  = threadIdx.x;
    const int base = blockIdx.x * BLK;

    // ---- cooperative float4 load of this block's 768 log_scale floats ----
    // sbase4 = blockIdx*192 (float4-aligned since 256*3/4 = 192)
    if (tid < 192) {
        const int idx4 = blockIdx.x * 192 + tid;
        if (idx4 < n_ls4) {
            ((f32x4*)s_scale)[tid] = __builtin_nontemporal_load(&ls4[idx4]);
        }
    }
    __syncthreads();

    const int i = base + tid;
    if (i < n) {
        f32x4 q = __builtin_nontemporal_load(&quats[i]);  // coalesced 16B/lane
        float w = q.x, x = q.y, y = q.z, z = q.w;
        float inv = rsqrtf(fmaf(w, w, fmaf(x, x, fmaf(y, y, z * z))));
        w *= inv; x *= inv; y *= inv; z *= inv;

        // stride-3 LDS read: gcd(3,32)=1 -> conflict-free
        float s0 = __expf(s_scale[tid * 3 + 0]);
        float s1 = __expf(s_scale[tid * 3 + 1]);
        float s2 = __expf(s_scale[tid * 3 + 2]);

        // rotation matrix
        float r00 = 1.0f - 2.0f * (y * y + z * z);
        float r01 = 2.0f * (x * y - w * z);
        float r02 = 2.0f * (x * z + w * y);
        float r10 = 2.0f * (x * y + w * z);
        float r11 = 1.0f - 2.0f * (x * x + z * z);
        float r12 = 2.0f * (y * z - w * x);
        float r20 = 2.0f * (x * z - w * y);
        float r21 = 2.0f * (y * z + w * x);
        float r22 = 1.0f - 2.0f * (x * x + y * y);

        // M = R * diag(s)
        float m00 = r00 * s0, m01 = r01 * s1, m02 = r02 * s2;
        float m10 = r10 * s0, m11 = r11 * s1, m12 = r12 * s2;
        float m20 = r20 * s0, m21 = r21 * s1, m22 = r22 * s2;

        // Sigma = M * M^T (symmetric, 6 unique)
        float c00 = fmaf(m00, m00, fmaf(m01, m01, m02 * m02));
        float c01 = fmaf(m00, m10, fmaf(m01, m11, m02 * m12));
        float c02 = fmaf(m00, m20, fmaf(m01, m21, m02 * m22));
        float c11 = fmaf(m10, m10, fmaf(m11, m11, m12 * m12));
        float c12 = fmaf(m10, m20, fmaf(m11, m21, m12 * m22));
        float c22 = fmaf(m20, m20, fmaf(m21, m21, m22 * m22));

        // stride-9 LDS write: gcd(9,32)=1 -> conflict-free
        float* o = &s_out[tid * 9];
        o[0] = c00; o[1] = c01; o[2] = c02;
        o[3] = c01; o[4] = c11; o[5] = c12;
        o[6] = c02; o[7] = c12; o[8] = c22;
    }
    __syncthreads();

    // ---- cooperative float4 store of the block's 2304 output floats ----
    // obase4 = blockIdx*576 (float4-aligned since 256*9/4 = 576)
    const int obase4 = blockIdx.x * 576;
#pragma unroll
    for (int r = 0; r < 3; ++r) {
        const int t = r * BLK + tid;     // 0..767; need t < 576
        if (t < 576) {
            const int idx4 = obase4 + t;
            if (idx4 < n_out4) {
                __builtin_nontemporal_store(((const f32x4*)s_out)[t], &out4[idx4]);
            }
        }
    }
}

extern "C" void kernel_launch(void* const* d_in, const int* in_sizes, int n_in,
                              void* d_out, int out_size, void* d_ws, size_t ws_size,
                              hipStream_t stream) {
    const f32x4* quats = (const f32x4*)d_in[0];
    const f32x4* ls4   = (const f32x4*)d_in[1];
    f32x4*       out4  = (f32x4*)d_out;

    const int n      = in_sizes[0] / 4;   // quats is [N,4]
    const int n_ls4  = in_sizes[1] / 4;   // N*3/4 (N*3 divisible by 4 for N=2M)
    const int n_out4 = out_size / 4;      // N*9/4
    const int nblocks = (n + BLK - 1) / BLK;
    gauss_covar_kernel<<<nblocks, BLK, 0, stream>>>(quats, ls4, out4, n, n_ls4, n_out4);
}